// Round 6
// baseline (98.605 us; speedup 1.0000x reference)
//
#include <hip/hip_runtime.h>
#include <math.h>

namespace {
constexpr int Bn = 4, Cn = 3, Hn = 96, Wn = 96;
constexpr int HWn = Hn * Wn;          // 9216
constexpr int NP  = Bn * Cn;          // 12 (batch,class) pairs
constexpr int NBLK1 = (Bn * HWn) / 256;   // 144 blocks in K1, 36 per image
constexpr int SENT = 62500;           // "no boundary in column" d^2 (> 9025+9025)

// ws layout in 4-byte words (~70 KB total):
// flags: [B][HW] bytes at word offset 0. Byte = pc(2b) | label(2b) | bda(1b) | bdb(1b)
constexpr int FLAG_WORDS = Bn * HWn / 4;          // 9216
constexpr int CNT_OFF  = FLAG_WORDS;              // [144][8] per-block partial counts
constexpr int NA_OFF   = CNT_OFF + NBLK1 * 8;     // [12] n_a
constexpr int NB_OFF   = NA_OFF + NP;             // [12] n_b
constexpr int SUMF_OFF = NB_OFF + NP;             // [12] float sum_f
constexpr int SUMB_OFF = SUMF_OFF + NP;           // [12] float sum_b   (contiguous w/ SUMF)
constexpr int TICK_OFF = SUMB_OFF + NP + 4;       // ticket (padded)
constexpr int MK_OFF   = TICK_OFF + 12;           // [NP][6][96] column masks (w0..2=bd_a, w3..5=bd_b)
}

// K1: fused argmax + boundary flags + per-block partial counts.
// boundary = img*(5-new) > 0  <=>  in-mask && (#in-bounds same-class neighbors) < 4.
__global__ __launch_bounds__(256) void k_front(const float* __restrict__ preds,
                                               const int* __restrict__ labels,
                                               int* __restrict__ wi) {
    int blk = blockIdx.x, tid = threadIdx.x;
    int b = blk / 36;
    int p = (blk - b * 36) * 256 + tid;          // exact cover of [0, HW)
    int y = p / Wn, x = p - y * Wn;
    const float* pb = preds + (size_t)b * Cn * HWn;
    const int*   lb = labels + b * HWn;

    auto amax = [&](int q) -> int {              // strict > == jnp.argmax first-max
        float v0 = pb[q], v1 = pb[HWn + q], v2 = pb[2 * HWn + q];
        int bi = 0; float bv = v0;
        if (v1 > bv) { bv = v1; bi = 1; }
        if (v2 > bv) { bv = v2; bi = 2; }
        return bi;
    };
    int pc = amax(p);
    int l  = lb[p];
    int ca = 0, cb = 0;
    if (y > 0)      { ca += (amax(p - Wn) == pc); cb += (lb[p - Wn] == l); }
    if (y < Hn - 1) { ca += (amax(p + Wn) == pc); cb += (lb[p + Wn] == l); }
    if (x > 0)      { ca += (amax(p - 1)  == pc); cb += (lb[p - 1]  == l); }
    if (x < Wn - 1) { ca += (amax(p + 1)  == pc); cb += (lb[p + 1]  == l); }
    ((unsigned char*)wi)[b * HWn + p] =
        (unsigned char)(pc | (l << 2) | ((ca < 4) << 4) | ((cb < 4) << 5));

    // per-block counts: 6 ballots -> per-wave popcounts -> LDS -> one write
    __shared__ int wcnt[4][6];
    int wv = tid >> 6, ln = tid & 63;
    int cnts[6];
#pragma unroll
    for (int c = 0; c < 3; ++c) {
        cnts[c]     = __popcll(__ballot(pc == c));
        cnts[3 + c] = __popcll(__ballot(l == c));
    }
    if (ln == 0) {
        for (int k = 0; k < 6; ++k) wcnt[wv][k] = cnts[k];
    }
    __syncthreads();
    if (tid < 6)
        wi[CNT_OFF + blk * 8 + tid] = wcnt[0][tid] + wcnt[1][tid] + wcnt[2][tid] + wcnt[3][tid];
    if (blk == 0) {                  // zero K3's accumulators + ticket (stream-ordered before K3)
        if (tid < 24) wi[SUMF_OFF + tid] = 0;      // covers SUMF[12] + SUMB[12]
        if (tid == 24) wi[TICK_OFF] = 0;
    }
}

// K2: column boundary bitmasks from flag bytes (+ count aggregation in spare threads).
__global__ void k_masks(int* __restrict__ wi) {
    int t = blockIdx.x * blockDim.x + threadIdx.x;
    const unsigned char* flags = (const unsigned char*)wi;
    if (t < NP * 288) {
        int b = t / 864, rem = t - b * 864;
        int c = rem / 288, rem2 = rem - c * 288;
        int w = rem2 / 96, x = rem2 - w * 96;
        const unsigned char* fb = flags + b * HWn + x;
        unsigned am = 0, bm = 0;
#pragma unroll
        for (int k = 0; k < 32; ++k) {
            unsigned f = fb[(w * 32 + k) * Wn];
            am |= (unsigned)(((f >> 4) & 1) & (unsigned)((f & 3) == (unsigned)c)) << k;
            bm |= (unsigned)(((f >> 5) & 1) & (unsigned)(((f >> 2) & 3) == (unsigned)c)) << k;
        }
        int pr = b * Cn + c;
        wi[MK_OFF + pr * 576 + w * 96 + x]       = (int)am;
        wi[MK_OFF + pr * 576 + (w + 3) * 96 + x] = (int)bm;
    } else if (t < NP * 288 + 24) {
        int idx = t - NP * 288;
        int pr = idx % 12, which = idx / 12;     // 0 -> n_a, 1 -> n_b
        int b = pr / Cn, c = pr - b * Cn;
        int s = 0;
        for (int k = 0; k < 36; ++k) s += wi[CNT_OFF + (b * 36 + k) * 8 + which * 3 + c];
        wi[(which ? NB_OFF : NA_OFF) + pr] = s;
    }
}

// K3: fused EDT pass1 (bitmask nearest-set-bit) + pass2 (exact integer min G+dx^2)
// + masked sqrt sums + last-block finalization (ticket pattern).
__global__ __launch_bounds__(384) void k_edt_sum(int* __restrict__ wi,
                                                 float* __restrict__ wf,
                                                 float* __restrict__ out) {
    int pr = blockIdx.y;
    int rb = blockIdx.x;            // 0..23 (4-row band)
    int j  = threadIdx.x;           // 0..383
    int b = pr / Cn, c = pr - b * Cn;

    __shared__ unsigned int mlds[576];   // [6][96] column mask words
    __shared__ unsigned int glds[384];   // [4][96] packed u16: lo=G_bb(label), hi=G_ba(pred)
    __shared__ int lastflag;

    for (int k = j; k < 576; k += 384)
        mlds[k] = (unsigned int)wi[MK_OFF + pr * 576 + k];
    __syncthreads();

    int r = j / 96, xp = j - r * 96;
    int y = rb * 4 + r;

    unsigned long long alo = (unsigned long long)mlds[xp]
                           | ((unsigned long long)mlds[96 + xp] << 32);
    unsigned long long ahi = mlds[192 + xp];
    unsigned long long blo = (unsigned long long)mlds[288 + xp]
                           | ((unsigned long long)mlds[384 + xp] << 32);
    unsigned long long bhi = mlds[480 + xp];

    __uint128_t Ma = ((__uint128_t)ahi << 64) | alo;   // pred boundary
    __uint128_t Mb = ((__uint128_t)bhi << 64) | blo;   // label boundary

    auto dist1d = [&](__uint128_t M) -> int {
        int du = 200, dd = 200;
        __uint128_t s = M >> y;
        if (s) {
            unsigned long long lo = (unsigned long long)s;
            du = lo ? __builtin_ctzll(lo) : 64 + __builtin_ctzll((unsigned long long)(s >> 64));
        }
        s = M << (127 - y);
        if (s) {
            unsigned long long h = (unsigned long long)(s >> 64);
            dd = h ? __builtin_clzll(h) : 64 + __builtin_clzll((unsigned long long)s);
        }
        int d = min(du, dd);
        return (d >= Hn) ? SENT : d * d;
    };
    glds[j] = (unsigned)dist1d(Mb) | ((unsigned)dist1d(Ma) << 16);
    __syncthreads();

    // pass 2 for pixel (y, xp)
    int p = y * Wn + xp;
    unsigned f = ((const unsigned char*)wi)[b * HWn + p];
    int a  = ((f & 3) == (unsigned)c);
    int bm = (((f >> 2) & 3) == (unsigned)c);
    int na = wi[NA_OFF + pr];
    int nb = wi[NB_OFF + pr];
    // nonempty mask <=> nonempty boundary (edge pixels have <4 in-bounds nbrs)
    bool af = a && !bm && (nb > 0);
    bool bw = bm && !a && (na > 0);

    float s = 0.0f;
    if (af || bw) {
        int sh = af ? 0 : 16;
        int md2 = 0x7fffffff;
        const unsigned int* grow = &glds[r * 96];
#pragma unroll 8
        for (int q = 0; q < Wn; ++q) {
            int gs = (grow[q] >> sh) & 0xffff;
            int dx = xp - q;
            md2 = min(md2, gs + dx * dx);
        }
        s = sqrtf((float)md2);   // integer md2 <= 18050: fp32-exact, matches reference
    }
    float vF = af ? s : 0.0f;
    float vB = bw ? s : 0.0f;
#pragma unroll
    for (int off = 32; off >= 1; off >>= 1) {
        vF += __shfl_xor(vF, off, 64);
        vB += __shfl_xor(vB, off, 64);
    }
    if ((j & 63) == 0) {
        if (vF != 0.0f) atomicAdd(&wf[SUMF_OFF + pr], vF);
        if (vB != 0.0f) atomicAdd(&wf[SUMB_OFF + pr], vB);
    }

    // ticket: last of the 288 blocks finalizes the 25 outputs
    __syncthreads();                 // drains this block's atomics (waitcnt before barrier)
    if (j == 0) {
        __threadfence();
        int old = atomicAdd(&wi[TICK_OFF], 1);
        lastflag = (old == NP * 24 - 1);
    }
    __syncthreads();
    if (!lastflag) return;
    __threadfence();

    __shared__ float hds[12];
    __shared__ float fld[12];
    if (j < 12) {
        int nA = wi[NA_OFF + j];
        int nB = wi[NB_OFF + j];
        float sF = atomicAdd(&wf[SUMF_OFF + j], 0.0f);   // atomic load, device-coherent
        float sB = atomicAdd(&wf[SUMB_OFF + j], 0.0f);
        float h, fl = 0.0f;
        if (nA == 0) { h = (Hn + Wn) / 4.0f; fl = 1.0f; }
        else {
            h = fmaxf(sF / fmaxf((float)nA, 1.0f), sB / fmaxf((float)nB, 1.0f));
        }
        if (j % Cn == 0) { h = 0.0f; fl = 0.0f; }        // IGNORE class
        hds[j] = h; fld[j] = fl;
    }
    __syncthreads();
    if (j == 0) {
        float failed[3] = {0.f, 0.f, 0.f};
        for (int q = 0; q < 12; ++q) failed[q % 3] += fld[q];
        for (int bb = 0; bb < Bn; ++bb) {
            float* row = out + bb * (Cn + 2);
            float ssum = 0.f;
            for (int cc = 0; cc < Cn; ++cc) { row[cc] = hds[bb * 3 + cc]; ssum += row[cc]; }
            row[Cn]     = ssum / (float)Cn;
            row[Cn + 1] = (hds[bb * 3] + hds[bb * 3 + 1]) / (float)(Cn - 1);
        }
        float* Fc = out + Bn * (Cn + 2);
        float fs = 0.f;
        for (int cc = 0; cc < Cn; ++cc) { Fc[cc] = failed[cc]; fs += failed[cc]; }
        Fc[Cn]     = fs / (float)Cn;
        Fc[Cn + 1] = (failed[1] + failed[2]) / (float)(Cn - 1);
    }
}

extern "C" void kernel_launch(void* const* d_in, const int* in_sizes, int n_in,
                              void* d_out, int out_size, void* d_ws, size_t ws_size,
                              hipStream_t stream) {
    const float* preds  = (const float*)d_in[0];
    const int*   labels = (const int*)d_in[1];
    float* out = (float*)d_out;
    int*   wi = (int*)d_ws;
    float* wf = (float*)d_ws;

    // K1: argmax + boundary flags + partial counts (144 x 256)
    k_front<<<NBLK1, 256, 0, stream>>>(preds, labels, wi);
    // K2: column masks + count aggregation (3456+24 threads)
    k_masks<<<(NP * 288 + 24 + 255) / 256, 256, 0, stream>>>(wi);
    // K3: EDT + masked sums + last-block finalize (grid 24 x 12, 384 thr)
    dim3 g3(Hn / 4, NP);
    k_edt_sum<<<g3, 384, 0, stream>>>(wi, wf, out);
}

// Round 7
// 69.548 us; speedup vs baseline: 1.4178x; 1.4178x over previous
//
#include <hip/hip_runtime.h>
#include <math.h>

namespace {
constexpr int Bn = 4, Cn = 3, Hn = 96, Wn = 96;
constexpr int HWn = Hn * Wn;          // 9216
constexpr int NP  = Bn * Cn;          // 12 (batch,class) pairs
constexpr int NBLK1 = (Bn * HWn) / 256;   // 144 blocks in K1, 36 per image
constexpr int SENT = 62500;           // "no boundary in column" d^2 (> 9025+9025)

// ws layout in 4-byte words (~71 KB total).
// flags: [B][HW] bytes at word offset 0. Byte = pc(2b) | label(2b) | bda(1b) | bdb(1b)
constexpr int FLAG_WORDS = Bn * HWn / 4;          // 9216
constexpr int CNT_OFF  = FLAG_WORDS;              // [144][8] per-block partial counts
constexpr int NA_OFF   = CNT_OFF + NBLK1 * 8;     // [12] n_a (read-only after K2)
constexpr int NB_OFF   = NA_OFF + NP;             // [12] n_b
constexpr int SUM_OFF  = ((NB_OFF + NP + 15) / 16) * 16;  // line-aligned atomics region
// SUMF[pr] at SUM_OFF+pr*16, SUMB[pr] at SUM_OFF+(NP+pr)*16 -> one 64B line each
constexpr int SUM_WORDS = 2 * NP * 16;            // 384
constexpr int TICK_OFF = SUM_OFF + SUM_WORDS;     // ticket, own line
constexpr int ZERO_WORDS = SUM_WORDS + 16;        // sums + ticket line
constexpr int MK_OFF   = TICK_OFF + 16;           // [NP][6][96] column masks (w0..2=bd_a, w3..5=bd_b)

__device__ __forceinline__ int SUMF_I(int pr) { return SUM_OFF + pr * 16; }
__device__ __forceinline__ int SUMB_I(int pr) { return SUM_OFF + (NP + pr) * 16; }
}

// K1: fused argmax + boundary flags + per-block partial counts.
// boundary = img*(5-new) > 0  <=>  in-mask && (#in-bounds same-class neighbors) < 4.
__global__ __launch_bounds__(256) void k_front(const float* __restrict__ preds,
                                               const int* __restrict__ labels,
                                               int* __restrict__ wi) {
    int blk = blockIdx.x, tid = threadIdx.x;
    int b = blk / 36;
    int p = (blk - b * 36) * 256 + tid;          // exact cover of [0, HW)
    int y = p / Wn, x = p - y * Wn;
    const float* pb = preds + (size_t)b * Cn * HWn;
    const int*   lb = labels + b * HWn;

    auto amax = [&](int q) -> int {              // strict > == jnp.argmax first-max
        float v0 = pb[q], v1 = pb[HWn + q], v2 = pb[2 * HWn + q];
        int bi = 0; float bv = v0;
        if (v1 > bv) { bv = v1; bi = 1; }
        if (v2 > bv) { bv = v2; bi = 2; }
        return bi;
    };
    int pc = amax(p);
    int l  = lb[p];
    int ca = 0, cb = 0;
    if (y > 0)      { ca += (amax(p - Wn) == pc); cb += (lb[p - Wn] == l); }
    if (y < Hn - 1) { ca += (amax(p + Wn) == pc); cb += (lb[p + Wn] == l); }
    if (x > 0)      { ca += (amax(p - 1)  == pc); cb += (lb[p - 1]  == l); }
    if (x < Wn - 1) { ca += (amax(p + 1)  == pc); cb += (lb[p + 1]  == l); }
    ((unsigned char*)wi)[b * HWn + p] =
        (unsigned char)(pc | (l << 2) | ((ca < 4) << 4) | ((cb < 4) << 5));

    // per-block counts: 6 ballots -> per-wave popcounts -> LDS -> one write
    __shared__ int wcnt[4][6];
    int wv = tid >> 6, ln = tid & 63;
    int cnts[6];
#pragma unroll
    for (int c = 0; c < 3; ++c) {
        cnts[c]     = __popcll(__ballot(pc == c));
        cnts[3 + c] = __popcll(__ballot(l == c));
    }
    if (ln == 0) {
        for (int k = 0; k < 6; ++k) wcnt[wv][k] = cnts[k];
    }
    __syncthreads();
    if (tid < 6)
        wi[CNT_OFF + blk * 8 + tid] = wcnt[0][tid] + wcnt[1][tid] + wcnt[2][tid] + wcnt[3][tid];
    if (blk == 0) {                  // zero K3's accumulators + ticket (stream-ordered before K3)
        if (tid < ZERO_WORDS) wi[SUM_OFF + tid] = 0;
        if (tid + 256 < ZERO_WORDS) wi[SUM_OFF + tid + 256] = 0;
    }
}

// K2: column boundary bitmasks from flag bytes (+ count aggregation in spare threads).
__global__ void k_masks(int* __restrict__ wi) {
    int t = blockIdx.x * blockDim.x + threadIdx.x;
    const unsigned char* flags = (const unsigned char*)wi;
    if (t < NP * 288) {
        int b = t / 864, rem = t - b * 864;
        int c = rem / 288, rem2 = rem - c * 288;
        int w = rem2 / 96, x = rem2 - w * 96;
        const unsigned char* fb = flags + b * HWn + x;
        unsigned am = 0, bm = 0;
#pragma unroll
        for (int k = 0; k < 32; ++k) {
            unsigned f = fb[(w * 32 + k) * Wn];
            am |= (unsigned)(((f >> 4) & 1) & (unsigned)((f & 3) == (unsigned)c)) << k;
            bm |= (unsigned)(((f >> 5) & 1) & (unsigned)(((f >> 2) & 3) == (unsigned)c)) << k;
        }
        int pr = b * Cn + c;
        wi[MK_OFF + pr * 576 + w * 96 + x]       = (int)am;
        wi[MK_OFF + pr * 576 + (w + 3) * 96 + x] = (int)bm;
    } else if (t < NP * 288 + 24) {
        int idx = t - NP * 288;
        int pr = idx % 12, which = idx / 12;     // 0 -> n_a, 1 -> n_b
        int b = pr / Cn, c = pr - b * Cn;
        int s = 0;
        for (int k = 0; k < 36; ++k) s += wi[CNT_OFF + (b * 36 + k) * 8 + which * 3 + c];
        wi[(which ? NB_OFF : NA_OFF) + pr] = s;
    }
}

// K3: fused EDT pass1 (bitmask nearest-set-bit) + pass2 (exact integer min G+dx^2)
// + masked sqrt sums (block-reduced, <=2 atomics/block on private cachelines)
// + last-block finalization (ticket pattern).
__global__ __launch_bounds__(384) void k_edt_sum(int* __restrict__ wi,
                                                 float* __restrict__ wf,
                                                 float* __restrict__ out) {
    int pr = blockIdx.y;
    int rb = blockIdx.x;            // 0..23 (4-row band)
    int j  = threadIdx.x;           // 0..383
    int b = pr / Cn, c = pr - b * Cn;

    __shared__ unsigned int mlds[576];   // [6][96] column mask words
    __shared__ unsigned int glds[384];   // [4][96] packed u16: lo=G_bb(label), hi=G_ba(pred)
    __shared__ float sF6[6], sB6[6];
    __shared__ int lastflag;

    for (int k = j; k < 576; k += 384)
        mlds[k] = (unsigned int)wi[MK_OFF + pr * 576 + k];
    __syncthreads();

    int r = j / 96, xp = j - r * 96;
    int y = rb * 4 + r;

    unsigned long long alo = (unsigned long long)mlds[xp]
                           | ((unsigned long long)mlds[96 + xp] << 32);
    unsigned long long ahi = mlds[192 + xp];
    unsigned long long blo = (unsigned long long)mlds[288 + xp]
                           | ((unsigned long long)mlds[384 + xp] << 32);
    unsigned long long bhi = mlds[480 + xp];

    __uint128_t Ma = ((__uint128_t)ahi << 64) | alo;   // pred boundary
    __uint128_t Mb = ((__uint128_t)bhi << 64) | blo;   // label boundary

    auto dist1d = [&](__uint128_t M) -> int {
        int du = 200, dd = 200;
        __uint128_t s = M >> y;
        if (s) {
            unsigned long long lo = (unsigned long long)s;
            du = lo ? __builtin_ctzll(lo) : 64 + __builtin_ctzll((unsigned long long)(s >> 64));
        }
        s = M << (127 - y);
        if (s) {
            unsigned long long h = (unsigned long long)(s >> 64);
            dd = h ? __builtin_clzll(h) : 64 + __builtin_clzll((unsigned long long)s);
        }
        int d = min(du, dd);
        return (d >= Hn) ? SENT : d * d;
    };
    glds[j] = (unsigned)dist1d(Mb) | ((unsigned)dist1d(Ma) << 16);
    __syncthreads();

    // pass 2 for pixel (y, xp)
    int p = y * Wn + xp;
    unsigned f = ((const unsigned char*)wi)[b * HWn + p];
    int a  = ((f & 3) == (unsigned)c);
    int bm = (((f >> 2) & 3) == (unsigned)c);
    int na = wi[NA_OFF + pr];
    int nb = wi[NB_OFF + pr];
    // nonempty mask <=> nonempty boundary (edge pixels have <4 in-bounds nbrs)
    bool af = a && !bm && (nb > 0);
    bool bw = bm && !a && (na > 0);

    float s = 0.0f;
    if (af || bw) {
        int sh = af ? 0 : 16;
        int md2 = 0x7fffffff;
        const unsigned int* grow = &glds[r * 96];
#pragma unroll 8
        for (int q = 0; q < Wn; ++q) {
            int gs = (grow[q] >> sh) & 0xffff;
            int dx = xp - q;
            md2 = min(md2, gs + dx * dx);
        }
        s = sqrtf((float)md2);   // integer md2 <= 18050: fp32-exact, matches reference
    }
    float vF = af ? s : 0.0f;
    float vB = bw ? s : 0.0f;
#pragma unroll
    for (int off = 32; off >= 1; off >>= 1) {
        vF += __shfl_xor(vF, off, 64);
        vB += __shfl_xor(vB, off, 64);
    }
    int wv = j >> 6;
    if ((j & 63) == 0) { sF6[wv] = vF; sB6[wv] = vB; }
    __syncthreads();
    // <=2 atomics per block, each target owns a 64B line (12+12 lines total)
    if (j == 0) {
        float t = sF6[0] + sF6[1] + sF6[2] + sF6[3] + sF6[4] + sF6[5];
        if (t != 0.0f) atomicAdd(&wf[SUMF_I(pr)], t);
    } else if (j == 64) {
        float t = sB6[0] + sB6[1] + sB6[2] + sB6[3] + sB6[4] + sB6[5];
        if (t != 0.0f) atomicAdd(&wf[SUMB_I(pr)], t);
    }

    // ticket: last of the 288 blocks finalizes the 25 outputs.
    // __syncthreads drains each wave's outstanding atomics (s_waitcnt before
    // s_barrier), so sum-atomics are at the coherence point before the ticket.
    __syncthreads();
    if (j == 0) {
        int old = atomicAdd(&wi[TICK_OFF], 1);
        lastflag = (old == NP * 24 - 1);
    }
    __syncthreads();
    if (!lastflag) return;

    __shared__ float hds[12];
    __shared__ float fld[12];
    if (j < 12) {
        int nA = wi[NA_OFF + j];
        int nB = wi[NB_OFF + j];
        float sFv = atomicAdd(&wf[SUMF_I(j)], 0.0f);   // device-coherent atomic load
        float sBv = atomicAdd(&wf[SUMB_I(j)], 0.0f);
        float h, fl = 0.0f;
        if (nA == 0) { h = (Hn + Wn) / 4.0f; fl = 1.0f; }
        else {
            h = fmaxf(sFv / fmaxf((float)nA, 1.0f), sBv / fmaxf((float)nB, 1.0f));
        }
        if (j % Cn == 0) { h = 0.0f; fl = 0.0f; }      // IGNORE class
        hds[j] = h; fld[j] = fl;
    }
    __syncthreads();
    if (j == 0) {
        float failed[3] = {0.f, 0.f, 0.f};
        for (int q = 0; q < 12; ++q) failed[q % 3] += fld[q];
        for (int bb = 0; bb < Bn; ++bb) {
            float* row = out + bb * (Cn + 2);
            float ssum = 0.f;
            for (int cc = 0; cc < Cn; ++cc) { row[cc] = hds[bb * 3 + cc]; ssum += row[cc]; }
            row[Cn]     = ssum / (float)Cn;
            row[Cn + 1] = (hds[bb * 3] + hds[bb * 3 + 1]) / (float)(Cn - 1);
        }
        float* Fc = out + Bn * (Cn + 2);
        float fs = 0.f;
        for (int cc = 0; cc < Cn; ++cc) { Fc[cc] = failed[cc]; fs += failed[cc]; }
        Fc[Cn]     = fs / (float)Cn;
        Fc[Cn + 1] = (failed[1] + failed[2]) / (float)(Cn - 1);
    }
}

extern "C" void kernel_launch(void* const* d_in, const int* in_sizes, int n_in,
                              void* d_out, int out_size, void* d_ws, size_t ws_size,
                              hipStream_t stream) {
    const float* preds  = (const float*)d_in[0];
    const int*   labels = (const int*)d_in[1];
    float* out = (float*)d_out;
    int*   wi = (int*)d_ws;
    float* wf = (float*)d_ws;

    // K1: argmax + boundary flags + partial counts (144 x 256)
    k_front<<<NBLK1, 256, 0, stream>>>(preds, labels, wi);
    // K2: column masks + count aggregation (3456+24 threads)
    k_masks<<<(NP * 288 + 24 + 255) / 256, 256, 0, stream>>>(wi);
    // K3: EDT + masked sums + last-block finalize (grid 24 x 12, 384 thr)
    dim3 g3(Hn / 4, NP);
    k_edt_sum<<<g3, 384, 0, stream>>>(wi, wf, out);
}